// Round 15
// baseline (258.781 us; speedup 1.0000x reference)
//
#include <hip/hip_runtime.h>
#include <hip/hip_bf16.h>

typedef __bf16 bf16x8 __attribute__((ext_vector_type(8)));
typedef __bf16 bf16x4 __attribute__((ext_vector_type(4)));
typedef float  f32x4  __attribute__((ext_vector_type(4)));

#define MFMA16(a, b, c) __builtin_amdgcn_mfma_f32_16x16x32_bf16((a), (b), (c), 0, 0, 0)
#define GLD16(g, l)                                                              \
    __builtin_amdgcn_global_load_lds(                                            \
        (const __attribute__((address_space(1))) void*)(g),                      \
        (__attribute__((address_space(3))) void*)(l), 16, 0, 0)

// ------------- fused fp32 -> bf16 convert for all three tensors (1 launch) ------
__global__ __launch_bounds__(256) void cvt3_f32_bf16(const float* __restrict__ a, __bf16* __restrict__ oa, int na,
                                                     const float* __restrict__ b, __bf16* __restrict__ ob, int nb,
                                                     const float* __restrict__ c, __bf16* __restrict__ oc, int nc) {
    const int stride = gridDim.x * blockDim.x * 4;
    const int start = (blockIdx.x * blockDim.x + threadIdx.x) * 4;
    for (int i = start; i < na; i += stride) {
        float4 v = *(const float4*)(a + i);
        bf16x4 o; o[0] = (__bf16)v.x; o[1] = (__bf16)v.y; o[2] = (__bf16)v.z; o[3] = (__bf16)v.w;
        *(bf16x4*)(oa + i) = o;
    }
    for (int i = start; i < nb; i += stride) {
        float4 v = *(const float4*)(b + i);
        bf16x4 o; o[0] = (__bf16)v.x; o[1] = (__bf16)v.y; o[2] = (__bf16)v.z; o[3] = (__bf16)v.w;
        *(bf16x4*)(ob + i) = o;
    }
    for (int i = start; i < nc; i += stride) {
        float4 v = *(const float4*)(c + i);
        bf16x4 o; o[0] = (__bf16)v.x; o[1] = (__bf16)v.y; o[2] = (__bf16)v.z; o[3] = (__bf16)v.w;
        *(bf16x4*)(oc + i) = o;
    }
}

// ---------------- QKV GEMM (m97 + XCD swizzle + LDS-transposed V epilogue) -------
__global__ __launch_bounds__(256, 2) void qkv_gemm(const __bf16* __restrict__ X,
                                                   const __bf16* __restrict__ W,
                                                   const float* __restrict__ bias,
                                                   __bf16* __restrict__ Qo,
                                                   __bf16* __restrict__ Ko,
                                                   __bf16* __restrict__ VTo) {
    const int KD = 1024;
    __shared__ __align__(16) char smem[34816];   // As 8K | Bs 8K ; V-epilogue reuses all
    __bf16* As = (__bf16*)smem;
    __bf16* Bs = (__bf16*)(smem + 8192);
    const int tid = threadIdx.x;
    const int lane = tid & 63, w = tid >> 6;
    const int lr = lane & 15, lg = lane >> 4;
    const int orig = blockIdx.x;                       // 0..1535
    const int wgid = (orig & 7) * 192 + (orig >> 3);   // bijective (1536 % 8 == 0)
    const int row0 = (wgid & 63) * 128, col0 = (wgid >> 6) * 128;
    const int wrow = (w >> 1) * 64, wcol = (w & 1) * 64;
    f32x4 acc[4][4] = {};
    const int c0 = tid, c1 = tid + 256;
    const __bf16* ga0 = X + (size_t)(row0 + (c0 >> 2)) * KD + (c0 & 3) * 8;
    const __bf16* ga1 = X + (size_t)(row0 + (c1 >> 2)) * KD + (c1 & 3) * 8;
    const __bf16* gb0 = W + (size_t)(col0 + (c0 >> 2)) * KD + (c0 & 3) * 8;
    const __bf16* gb1 = W + (size_t)(col0 + (c1 >> 2)) * KD + (c1 & 3) * 8;
    for (int k0 = 0; k0 < KD; k0 += 32) {
        __syncthreads();
        GLD16(ga0 + k0, As + c0 * 8);
        GLD16(ga1 + k0, As + c1 * 8);
        GLD16(gb0 + k0, Bs + c0 * 8);
        GLD16(gb1 + k0, Bs + c1 * 8);
        __syncthreads();
        bf16x8 a[4], b[4];
#pragma unroll
        for (int mi = 0; mi < 4; mi++)
            a[mi] = *(const bf16x8*)&As[(wrow + mi * 16 + lr) * 32 + lg * 8];
#pragma unroll
        for (int ni = 0; ni < 4; ni++)
            b[ni] = *(const bf16x8*)&Bs[(wcol + ni * 16 + lr) * 32 + lg * 8];
#pragma unroll
        for (int mi = 0; mi < 4; mi++)
#pragma unroll
            for (int ni = 0; ni < 4; ni++)
                acc[mi][ni] = MFMA16(a[mi], b[ni], acc[mi][ni]);
    }

    if (col0 < 2048) {
        const int sec = col0 >> 10;
#pragma unroll
        for (int mi = 0; mi < 4; mi++)
#pragma unroll
            for (int ni = 0; ni < 4; ni++)
#pragma unroll
                for (int r = 0; r < 4; r++) {
                    int m = row0 + wrow + mi * 16 + lg * 4 + r;
                    int n = col0 + wcol + ni * 16 + lr;
                    float v = acc[mi][ni][r] + bias[n];
                    int b_ = m >> 11, t = m & 2047;
                    int c = n & 1023;
                    int h = c >> 6, d = c & 63;
                    int bh = b_ * 16 + h;
                    if (sec == 0) Qo[(size_t)(bh * 2048 + t) * 64 + d] = (__bf16)(v * 0.125f);
                    else          Ko[(size_t)(bh * 2048 + t) * 64 + d] = (__bf16)v;
                }
    } else {
        __syncthreads();
        __bf16* vt = (__bf16*)smem;          // [128 ch][136] padded
#pragma unroll
        for (int mi = 0; mi < 4; mi++)
#pragma unroll
            for (int ni = 0; ni < 4; ni++) {
                int cl = wcol + ni * 16 + lr;
                int tl = wrow + mi * 16 + lg * 4;
                int n = col0 + cl;
                bf16x4 pk;
#pragma unroll
                for (int r = 0; r < 4; r++)
                    pk[r] = (__bf16)(acc[mi][ni][r] + bias[n]);
                *(bf16x4*)&vt[cl * 136 + tl] = pk;
            }
        __syncthreads();
        const int b_ = row0 >> 11, t_base = row0 & 2047;
        const int cl = tid >> 1, t0 = (tid & 1) * 64;
        const int c = (col0 + cl) & 1023;
        const int bh = b_ * 16 + (c >> 6), dd = c & 63;
        __bf16* dst = VTo + ((size_t)(bh * 64 + dd)) * 2048 + t_base + t0;
        const __bf16* src = &vt[cl * 136 + t0];
#pragma unroll
        for (int i = 0; i < 8; i++)
            *(bf16x8*)(dst + i * 8) = *(const bf16x8*)(src + i * 8);
    }
}

// ---------------- causal flash attention (dual-chain in-wave ILP) ----------------
// 512 blocks x 4 waves = 2048 uniform independent waves. Wave owns q-tile pair
// {idx, 63-idx}; each panel's k-range is split into low/high halves processed as
// TWO INDEPENDENT IN-WAVE CHAINS (separate m/l/o state + P-slabs, merged
// in-register at panel end, zero cross-wave coupling). 17 dual-iterations per
// wave instead of 33 single tiles: the second chain's issue fills the ~65%
// dependency-stall measured on the single-chain champion. Single rare-path
// combined rescale branch keeps the dual body one schedulable block.
__global__ __launch_bounds__(256) void attn_kernel(const __bf16* __restrict__ Q,
                                                   const __bf16* __restrict__ Km,
                                                   const __bf16* __restrict__ VT,
                                                   __bf16* __restrict__ ATT) {
    const int T = 2048, D = 64;
    __shared__ __align__(16) __bf16 plds[4][2][32][68];  // padded, per wave x half
    const int lane = threadIdx.x & 63, w = threadIdx.x >> 6;
    const int lr = lane & 15, lg = lane >> 4;
    const int orig = blockIdx.x;
    const int wgid = (orig & 7) * 64 + (orig >> 3);  // bijective XCD swizzle
    const int bh = wgid >> 3;
    const int idx = (wgid & 7) * 4 + w;              // 0..31
    const int b_ = bh >> 4, hh = bh & 15;
    const __bf16* Qp = Q + (size_t)bh * T * D;
    const __bf16* Kp = Km + (size_t)bh * T * D;
    const __bf16* Vp = VT + (size_t)bh * D * T;
    __bf16* slabA = &plds[w][0][0][0];
    __bf16* slabB = &plds[w][1][0][0];

    for (int ph = 0; ph < 2; ++ph) {
        const int j = ph ? 63 - idx : idx;
        const int qrow0 = j * 32;
        bf16x8 qa[2][2];
#pragma unroll
        for (int qt = 0; qt < 2; qt++)
#pragma unroll
            for (int dk = 0; dk < 2; dk++)
                qa[qt][dk] = *(const bf16x8*)(Qp + (size_t)(qrow0 + qt * 16 + lr) * D + dk * 32 + lg * 8);

        auto qk = [&](int kb, f32x4 (&s)[2][4]) {
            bf16x8 kf[4][2];
#pragma unroll
            for (int kt = 0; kt < 4; kt++)
#pragma unroll
                for (int dk = 0; dk < 2; dk++)
                    kf[kt][dk] = *(const bf16x8*)(Kp + (size_t)(kb + kt * 16 + lr) * D + dk * 32 + lg * 8);
#pragma unroll
            for (int qt = 0; qt < 2; qt++)
#pragma unroll
                for (int kt = 0; kt < 4; kt++)
#pragma unroll
                    for (int dk = 0; dk < 2; dk++)
                        s[qt][kt] = MFMA16(qa[qt][dk], kf[kt][dk], s[qt][kt]);
        };
        auto maskmax = [&](int kb, f32x4 (&s)[2][4], float (&lm)[2][4],
                           float (&mrow)[2][4]) -> int {
            int flag = 0;
#pragma unroll
            for (int qt = 0; qt < 2; qt++)
#pragma unroll
                for (int r = 0; r < 4; r++) {
                    const int qq = qrow0 + qt * 16 + lg * 4 + r;
                    float mt = -1e30f;
#pragma unroll
                    for (int kt = 0; kt < 4; kt++) {
                        float v = (kb + kt * 16 + lr <= qq) ? s[qt][kt][r] : -1e30f;
                        s[qt][kt][r] = v;
                        mt = fmaxf(mt, v);
                    }
                    lm[qt][r] = mt;
                    flag |= (mt > mrow[qt][r] + 8.0f) ? 1 : 0;
                }
            return flag;
        };
        auto rescale = [&](float (&lm)[2][4], float (&mrow)[2][4],
                           float (&lsum)[2][4], f32x4 (&o)[2][4]) {
#pragma unroll
            for (int qt = 0; qt < 2; qt++)
#pragma unroll
                for (int r = 0; r < 4; r++) {
                    float mt = lm[qt][r];
#pragma unroll
                    for (int off = 1; off < 16; off <<= 1)
                        mt = fmaxf(mt, __shfl_xor(mt, off));
                    float mnew = fmaxf(mrow[qt][r], mt);
                    float al = __expf(mrow[qt][r] - mnew);
                    mrow[qt][r] = mnew;
                    lsum[qt][r] *= al;
#pragma unroll
                    for (int dt = 0; dt < 4; dt++) o[qt][dt][r] *= al;
                }
        };
        auto expsum = [&](f32x4 (&s)[2][4], float (&mrow)[2][4], float (&lsum)[2][4]) {
#pragma unroll
            for (int qt = 0; qt < 2; qt++)
#pragma unroll
                for (int r = 0; r < 4; r++) {
                    float rs = 0.f;
#pragma unroll
                    for (int kt = 0; kt < 4; kt++) {
                        float p = __expf(s[qt][kt][r] - mrow[qt][r]);
                        s[qt][kt][r] = p;
                        rs += p;
                    }
                    lsum[qt][r] += rs;
                }
        };
        auto pv = [&](int kb, f32x4 (&s)[2][4], f32x4 (&o)[2][4], __bf16* slab) {
#pragma unroll
            for (int qt = 0; qt < 2; qt++)
#pragma unroll
                for (int kt = 0; kt < 4; kt++)
#pragma unroll
                    for (int r = 0; r < 4; r++)
                        slab[(qt * 16 + lg * 4 + r) * 68 + kt * 16 + lr] = (__bf16)s[qt][kt][r];
            bf16x8 pa[2][2];
#pragma unroll
            for (int qt = 0; qt < 2; qt++)
#pragma unroll
                for (int kh = 0; kh < 2; kh++)
                    pa[qt][kh] = *(const bf16x8*)&slab[(qt * 16 + lr) * 68 + kh * 32 + lg * 8];
#pragma unroll
            for (int kh = 0; kh < 2; kh++) {
                bf16x8 vf[4];
#pragma unroll
                for (int dt = 0; dt < 4; dt++)
                    vf[dt] = *(const bf16x8*)(Vp + (size_t)(dt * 16 + lr) * T + kb + kh * 32 + lg * 8);
#pragma unroll
                for (int qt = 0; qt < 2; qt++)
#pragma unroll
                    for (int dt = 0; dt < 4; dt++)
                        o[qt][dt] = MFMA16(pa[qt][kh], vf[dt], o[qt][dt]);
            }
        };

        // two independent chains: A = low half, B = high half (owns diagonal)
        float mrA[2][4], lsA[2][4], mrB[2][4], lsB[2][4];
#pragma unroll
        for (int qt = 0; qt < 2; qt++)
#pragma unroll
            for (int r = 0; r < 4; r++) {
                mrA[qt][r] = -1e30f; lsA[qt][r] = 0.f;
                mrB[qt][r] = -1e30f; lsB[qt][r] = 0.f;
            }
        f32x4 oA[2][4] = {}, oB[2][4] = {};

        const int nkb = (j + 2) >> 1;
        const int mid = nkb >> 1;
        for (int it = 0; it < mid; ++it) {
            const int kbA = it * 64, kbB = (mid + it) * 64;
            f32x4 sA[2][4] = {}, sB[2][4] = {};
            qk(kbA, sA);
            qk(kbB, sB);
            float lmA[2][4], lmB[2][4];
            int fA = maskmax(kbA, sA, lmA, mrA);
            int fB = maskmax(kbB, sB, lmB, mrB);
            if (__any(fA | fB)) {            // rare; rescale both (idempotent-safe)
                rescale(lmA, mrA, lsA, oA);
                rescale(lmB, mrB, lsB, oB);
            }
            expsum(sA, mrA, lsA);
            expsum(sB, mrB, lsB);
            pv(kbA, sA, oA, slabA);
            pv(kbB, sB, oB, slabB);
        }
        if (nkb & 1) {                       // odd tail: single B tile (diagonal)
            const int kbB = (nkb - 1) * 64;
            f32x4 sB[2][4] = {};
            qk(kbB, sB);
            float lmB[2][4];
            int fB = maskmax(kbB, sB, lmB, mrB);
            if (__any(fB)) rescale(lmB, mrB, lsB, oB);
            expsum(sB, mrB, lsB);
            pv(kbB, sB, oB, slabB);
        }

        // merge A into B (in-register, exact)
#pragma unroll
        for (int qt = 0; qt < 2; qt++)
#pragma unroll
            for (int r = 0; r < 4; r++) {
                float m = fmaxf(mrA[qt][r], mrB[qt][r]);
                float aA = __expf(mrA[qt][r] - m);
                float aB = __expf(mrB[qt][r] - m);
                lsB[qt][r] = lsA[qt][r] * aA + lsB[qt][r] * aB;
#pragma unroll
                for (int dt = 0; dt < 4; dt++)
                    oB[qt][dt][r] = oA[qt][dt][r] * aA + oB[qt][dt][r] * aB;
            }

        // final row-sum reduce + normalize + store
#pragma unroll
        for (int qt = 0; qt < 2; qt++)
#pragma unroll
            for (int r = 0; r < 4; r++) {
                float rs = lsB[qt][r];
#pragma unroll
                for (int off = 1; off < 16; off <<= 1)
                    rs += __shfl_xor(rs, off);
                lsB[qt][r] = 1.0f / rs;
            }
#pragma unroll
        for (int qt = 0; qt < 2; qt++)
#pragma unroll
            for (int dt = 0; dt < 4; dt++)
#pragma unroll
                for (int r = 0; r < 4; r++) {
                    int qq = qrow0 + qt * 16 + lg * 4 + r;
                    int dd = dt * 16 + lr;
                    float val = oB[qt][dt][r] * lsB[qt][r];
                    ATT[(size_t)(b_ * 2048 + qq) * 1024 + hh * 64 + dd] = (__bf16)val;
                }
    }
}

// ---------------- proj GEMM (m97 structure + XCD-chunked swizzle) ----------------
__global__ __launch_bounds__(256, 2) void proj_gemm(const __bf16* __restrict__ A,
                                                    const __bf16* __restrict__ W,
                                                    const float* __restrict__ bias,
                                                    float* __restrict__ out) {
    const int KD = 1024;
    __shared__ __align__(16) __bf16 As[128 * 32];
    __shared__ __align__(16) __bf16 Bs[128 * 32];
    const int tid = threadIdx.x;
    const int lane = tid & 63, w = tid >> 6;
    const int lr = lane & 15, lg = lane >> 4;
    const int orig = blockIdx.x;                       // 0..511
    const int wgid = (orig & 7) * 64 + (orig >> 3);
    const int row0 = (wgid & 63) * 128, col0 = (wgid >> 6) * 128;
    const int wrow = (w >> 1) * 64, wcol = (w & 1) * 64;
    f32x4 acc[4][4] = {};
    const int c0 = tid, c1 = tid + 256;
    const __bf16* ga0 = A + (size_t)(row0 + (c0 >> 2)) * KD + (c0 & 3) * 8;
    const __bf16* ga1 = A + (size_t)(row0 + (c1 >> 2)) * KD + (c1 & 3) * 8;
    const __bf16* gb0 = W + (size_t)(col0 + (c0 >> 2)) * KD + (c0 & 3) * 8;
    const __bf16* gb1 = W + (size_t)(col0 + (c1 >> 2)) * KD + (c1 & 3) * 8;
    for (int k0 = 0; k0 < KD; k0 += 32) {
        __syncthreads();
        GLD16(ga0 + k0, As + c0 * 8);
        GLD16(ga1 + k0, As + c1 * 8);
        GLD16(gb0 + k0, Bs + c0 * 8);
        GLD16(gb1 + k0, Bs + c1 * 8);
        __syncthreads();
        bf16x8 a[4], b[4];
#pragma unroll
        for (int mi = 0; mi < 4; mi++)
            a[mi] = *(const bf16x8*)&As[(wrow + mi * 16 + lr) * 32 + lg * 8];
#pragma unroll
        for (int ni = 0; ni < 4; ni++)
            b[ni] = *(const bf16x8*)&Bs[(wcol + ni * 16 + lr) * 32 + lg * 8];
#pragma unroll
        for (int mi = 0; mi < 4; mi++)
#pragma unroll
            for (int ni = 0; ni < 4; ni++)
                acc[mi][ni] = MFMA16(a[mi], b[ni], acc[mi][ni]);
    }
#pragma unroll
    for (int mi = 0; mi < 4; mi++)
#pragma unroll
        for (int ni = 0; ni < 4; ni++)
#pragma unroll
            for (int r = 0; r < 4; r++) {
                int m = row0 + wrow + mi * 16 + lg * 4 + r;
                int n = col0 + wcol + ni * 16 + lr;
                out[(size_t)m * 1024 + n] = acc[mi][ni][r] + bias[n];
            }
}

extern "C" void kernel_launch(void* const* d_in, const int* in_sizes, int n_in,
                              void* d_out, int out_size, void* d_ws, size_t ws_size,
                              hipStream_t stream) {
    const float* x      = (const float*)d_in[0];
    const float* qkv_w  = (const float*)d_in[1];
    const float* qkv_b  = (const float*)d_in[2];
    const float* proj_w = (const float*)d_in[3];
    const float* proj_b = (const float*)d_in[4];
    float* out = (float*)d_out;
    char* ws = (char*)d_ws;

    __bf16* xb    = (__bf16*)(ws);                         // 16 MB (reused as attb)
    __bf16* wqkv  = (__bf16*)(ws + 16777216);              //  6 MB
    __bf16* wproj = (__bf16*)(ws + 23068672);              //  2 MB
    __bf16* qb    = (__bf16*)(ws + 25165824);              // 16 MB
    __bf16* kb    = (__bf16*)(ws + 41943040);              // 16 MB
    __bf16* vtb   = (__bf16*)(ws + 58720256);              // 16 MB
    __bf16* attb  = xb;

    cvt3_f32_bf16<<<2048, 256, 0, stream>>>(x, xb, 4 * 2048 * 1024,
                                            qkv_w, wqkv, 3072 * 1024,
                                            proj_w, wproj, 1024 * 1024);
    qkv_gemm<<<1536, 256, 0, stream>>>(xb, wqkv, qkv_b, qb, kb, vtb);
    attn_kernel<<<512, 256, 0, stream>>>(qb, kb, vtb, attb);
    proj_gemm<<<512, 256, 0, stream>>>(attb, wproj, proj_b, out);
}

// Round 16
// 191.643 us; speedup vs baseline: 1.3503x; 1.3503x over previous
//
#include <hip/hip_runtime.h>
#include <hip/hip_bf16.h>

typedef __bf16 bf16x8 __attribute__((ext_vector_type(8)));
typedef __bf16 bf16x4 __attribute__((ext_vector_type(4)));
typedef float  f32x4  __attribute__((ext_vector_type(4)));

#define MFMA16(a, b, c) __builtin_amdgcn_mfma_f32_16x16x32_bf16((a), (b), (c), 0, 0, 0)
#define GLD16(g, l)                                                              \
    __builtin_amdgcn_global_load_lds(                                            \
        (const __attribute__((address_space(1))) void*)(g),                      \
        (__attribute__((address_space(3))) void*)(l), 16, 0, 0)

// ------------- fused fp32 -> bf16 convert for all three tensors (1 launch) ------
__global__ __launch_bounds__(256) void cvt3_f32_bf16(const float* __restrict__ a, __bf16* __restrict__ oa, int na,
                                                     const float* __restrict__ b, __bf16* __restrict__ ob, int nb,
                                                     const float* __restrict__ c, __bf16* __restrict__ oc, int nc) {
    const int stride = gridDim.x * blockDim.x * 4;
    const int start = (blockIdx.x * blockDim.x + threadIdx.x) * 4;
    for (int i = start; i < na; i += stride) {
        float4 v = *(const float4*)(a + i);
        bf16x4 o; o[0] = (__bf16)v.x; o[1] = (__bf16)v.y; o[2] = (__bf16)v.z; o[3] = (__bf16)v.w;
        *(bf16x4*)(oa + i) = o;
    }
    for (int i = start; i < nb; i += stride) {
        float4 v = *(const float4*)(b + i);
        bf16x4 o; o[0] = (__bf16)v.x; o[1] = (__bf16)v.y; o[2] = (__bf16)v.z; o[3] = (__bf16)v.w;
        *(bf16x4*)(ob + i) = o;
    }
    for (int i = start; i < nc; i += stride) {
        float4 v = *(const float4*)(c + i);
        bf16x4 o; o[0] = (__bf16)v.x; o[1] = (__bf16)v.y; o[2] = (__bf16)v.z; o[3] = (__bf16)v.w;
        *(bf16x4*)(oc + i) = o;
    }
}

// ---------------- QKV GEMM (m97 + XCD swizzle + fragment-native K/V epilogues) ---
// Q: [bh][t][64] pre-scaled by 0.125 (direct stores).
// K: fragment-native Kf[bh][kt16][dk][lane][8]: elem(k=kt16*16+(lane&15),
//    d=dk*32+(lane>>4)*8+e). Direct scatter (same coalescing class as before).
// V: fragment-native Vf[bh][kt32][dt][lane][8]: elem(k=kt32*32+(lane>>4)*8+e,
//    d=dt*16+(lane&15)). Routed through the LDS [ch][token] transpose ->
//    fully-coalesced 1KB stores. attn K/V loads become base+lane*16B (dense).
__global__ __launch_bounds__(256, 2) void qkv_gemm(const __bf16* __restrict__ X,
                                                   const __bf16* __restrict__ W,
                                                   const float* __restrict__ bias,
                                                   __bf16* __restrict__ Qo,
                                                   __bf16* __restrict__ Kf,
                                                   __bf16* __restrict__ Vf) {
    const int KD = 1024;
    __shared__ __align__(16) char smem[34816];   // As 8K | Bs 8K ; V-epilogue reuses
    __bf16* As = (__bf16*)smem;
    __bf16* Bs = (__bf16*)(smem + 8192);
    const int tid = threadIdx.x;
    const int lane = tid & 63, w = tid >> 6;
    const int lr = lane & 15, lg = lane >> 4;
    const int orig = blockIdx.x;                       // 0..1535
    const int wgid = (orig & 7) * 192 + (orig >> 3);   // bijective (1536 % 8 == 0)
    const int row0 = (wgid & 63) * 128, col0 = (wgid >> 6) * 128;
    const int wrow = (w >> 1) * 64, wcol = (w & 1) * 64;
    f32x4 acc[4][4] = {};
    const int c0 = tid, c1 = tid + 256;
    const __bf16* ga0 = X + (size_t)(row0 + (c0 >> 2)) * KD + (c0 & 3) * 8;
    const __bf16* ga1 = X + (size_t)(row0 + (c1 >> 2)) * KD + (c1 & 3) * 8;
    const __bf16* gb0 = W + (size_t)(col0 + (c0 >> 2)) * KD + (c0 & 3) * 8;
    const __bf16* gb1 = W + (size_t)(col0 + (c1 >> 2)) * KD + (c1 & 3) * 8;
    for (int k0 = 0; k0 < KD; k0 += 32) {
        __syncthreads();
        GLD16(ga0 + k0, As + c0 * 8);
        GLD16(ga1 + k0, As + c1 * 8);
        GLD16(gb0 + k0, Bs + c0 * 8);
        GLD16(gb1 + k0, Bs + c1 * 8);
        __syncthreads();
        bf16x8 a[4], b[4];
#pragma unroll
        for (int mi = 0; mi < 4; mi++)
            a[mi] = *(const bf16x8*)&As[(wrow + mi * 16 + lr) * 32 + lg * 8];
#pragma unroll
        for (int ni = 0; ni < 4; ni++)
            b[ni] = *(const bf16x8*)&Bs[(wcol + ni * 16 + lr) * 32 + lg * 8];
#pragma unroll
        for (int mi = 0; mi < 4; mi++)
#pragma unroll
            for (int ni = 0; ni < 4; ni++)
                acc[mi][ni] = MFMA16(a[mi], b[ni], acc[mi][ni]);
    }

    if (col0 < 1024) {
        // Q section: direct stores, pre-scaled by 0.125
#pragma unroll
        for (int mi = 0; mi < 4; mi++)
#pragma unroll
            for (int ni = 0; ni < 4; ni++)
#pragma unroll
                for (int r = 0; r < 4; r++) {
                    int m = row0 + wrow + mi * 16 + lg * 4 + r;
                    int n = col0 + wcol + ni * 16 + lr;
                    float v = acc[mi][ni][r] + bias[n];
                    int b_ = m >> 11, t = m & 2047;
                    int c = n & 1023;
                    int bh = b_ * 16 + (c >> 6), d = c & 63;
                    Qo[(size_t)(bh * 2048 + t) * 64 + d] = (__bf16)(v * 0.125f);
                }
    } else if (col0 < 2048) {
        // K section: direct scatter to fragment-native Kf
#pragma unroll
        for (int mi = 0; mi < 4; mi++)
#pragma unroll
            for (int ni = 0; ni < 4; ni++)
#pragma unroll
                for (int r = 0; r < 4; r++) {
                    int m = row0 + wrow + mi * 16 + lg * 4 + r;
                    int n = col0 + wcol + ni * 16 + lr;
                    float v = acc[mi][ni][r] + bias[n];
                    int b_ = m >> 11, t = m & 2047;
                    int c = n & 1023;
                    int bh = b_ * 16 + (c >> 6), d = c & 63;
                    size_t flat = (((size_t)bh * 128 + (t >> 4)) * 2 + (d >> 5)) * 512
                                + (((d & 31) >> 3) * 16 + (t & 15)) * 8 + (d & 7);
                    Kf[flat] = (__bf16)v;
                }
    } else {
        // V section: LDS [ch][token] transpose -> coalesced 1KB stores to Vf
        __syncthreads();                     // all waves done with As/Bs
        __bf16* vt = (__bf16*)smem;          // [128 ch][136] padded
#pragma unroll
        for (int mi = 0; mi < 4; mi++)
#pragma unroll
            for (int ni = 0; ni < 4; ni++) {
                int cl = wcol + ni * 16 + lr;            // channel-local 0..127
                int tl = wrow + mi * 16 + lg * 4;        // token-local base
                int n = col0 + cl;
                bf16x4 pk;
#pragma unroll
                for (int r = 0; r < 4; r++)
                    pk[r] = (__bf16)(acc[mi][ni][r] + bias[n]);
                *(bf16x4*)&vt[cl * 136 + tl] = pk;
            }
        __syncthreads();
        const int b_ = row0 >> 11, t_base = row0 & 2047;
        const int lane2 = tid & 63, w2 = tid >> 6;
        const int lr2 = lane2 & 15, lg2 = lane2 >> 4;
#pragma unroll
        for (int g = 0; g < 8; g++) {
            int group = g * 4 + w2;                      // 0..31
            int hh2 = group >> 4;                        // head-local 0..1
            int k32l = (group >> 2) & 3;                 // kt32 within tile
            int dt = group & 3;
            const __bf16* src = &vt[(hh2 * 64 + dt * 16 + lr2) * 136 + k32l * 32 + lg2 * 8];
            int c = (col0 & 1023) + hh2 * 64;
            int bh = b_ * 16 + (c >> 6);
            int kt32 = (t_base >> 5) + k32l;
            __bf16* dst = Vf + ((((size_t)bh * 64 + kt32) * 4 + dt) * 512) + lane2 * 8;
            *(bf16x8*)dst = *(const bf16x8*)src;
        }
    }
}

// ---------------- causal flash attention (r14 champion + fragment-native K/V) ----
// 512 blocks x 4 waves = 2048 uniform independent waves; wave owns q-tile pair
// {idx, 63-idx} = 33 k-tiles of 64. K/V loads are now base+lane*16B (dense 8-line
// transactions) from the fragment-native Kf/Vf buffers -> attacks the L1
// transaction count identified as the per-tile wall. Everything else identical
// to the 137us champion (no k-loop barriers, per-lane defer-max, padded P slab).
__global__ __launch_bounds__(256) void attn_kernel(const __bf16* __restrict__ Q,
                                                   const __bf16* __restrict__ Kf,
                                                   const __bf16* __restrict__ Vf,
                                                   __bf16* __restrict__ ATT) {
    const int T = 2048, D = 64;
    __shared__ __align__(16) __bf16 plds[4][32][68];  // padded: conflict-free
    const int lane = threadIdx.x & 63, w = threadIdx.x >> 6;
    const int lr = lane & 15, lg = lane >> 4;
    const int orig = blockIdx.x;
    const int wgid = (orig & 7) * 64 + (orig >> 3);   // bijective XCD swizzle
    const int bh = wgid >> 3;                 // 8 blocks per bh
    const int idx = (wgid & 7) * 4 + w;       // 0..31
    const int b_ = bh >> 4, hh = bh & 15;
    const __bf16* Qp  = Q  + (size_t)bh * T * D;
    const __bf16* Kfp = Kf + (size_t)bh * 131072;   // 128 kt16 x 2 dk x 512
    const __bf16* Vfp = Vf + (size_t)bh * 131072;   // 64 kt32 x 4 dt x 512

    for (int ph = 0; ph < 2; ++ph) {
        const int j = ph ? 63 - idx : idx;
        const int qrow0 = j * 32;
        bf16x8 qa[2][2];
#pragma unroll
        for (int qt = 0; qt < 2; qt++)
#pragma unroll
            for (int dk = 0; dk < 2; dk++)
                qa[qt][dk] = *(const bf16x8*)(Qp + (size_t)(qrow0 + qt * 16 + lr) * D + dk * 32 + lg * 8);

        float mrow[2][4], lsum[2][4];
#pragma unroll
        for (int qt = 0; qt < 2; qt++)
#pragma unroll
            for (int r = 0; r < 4; r++) { mrow[qt][r] = -1e30f; lsum[qt][r] = 0.f; }
        f32x4 o[2][4] = {};

        const int nkb = (j + 2) >> 1;
        for (int kt0 = 0; kt0 < nkb; ++kt0) {
            const int kb = kt0 * 64;
            bf16x8 kf[4][2];
#pragma unroll
            for (int kt = 0; kt < 4; kt++)
#pragma unroll
                for (int dk = 0; dk < 2; dk++)
                    kf[kt][dk] = *(const bf16x8*)(Kfp + (((kt0 * 4 + kt) * 2 + dk) << 9) + lane * 8);
            f32x4 s[2][4] = {};
#pragma unroll
            for (int qt = 0; qt < 2; qt++)
#pragma unroll
                for (int kt = 0; kt < 4; kt++)
#pragma unroll
                    for (int dk = 0; dk < 2; dk++)
                        s[qt][kt] = MFMA16(qa[qt][dk], kf[kt][dk], s[qt][kt]);

            // mask + per-lane local max (Q pre-scaled; no cross-lane common path)
            float lmax[2][4];
            int flag = 0;
#pragma unroll
            for (int qt = 0; qt < 2; qt++)
#pragma unroll
                for (int r = 0; r < 4; r++) {
                    const int qq = qrow0 + qt * 16 + lg * 4 + r;
                    float mt = -1e30f;
#pragma unroll
                    for (int kt = 0; kt < 4; kt++) {
                        float v = (kb + kt * 16 + lr <= qq) ? s[qt][kt][r] : -1e30f;
                        s[qt][kt][r] = v;
                        mt = fmaxf(mt, v);
                    }
                    lmax[qt][r] = mt;
                    flag |= (mt > mrow[qt][r] + 8.0f) ? 1 : 0;
                }

            // defer-max (T13): full reduce + rescale only when some row grew > 8
            if (__any(flag)) {
#pragma unroll
                for (int qt = 0; qt < 2; qt++)
#pragma unroll
                    for (int r = 0; r < 4; r++) {
                        float mt = lmax[qt][r];
#pragma unroll
                        for (int off = 1; off < 16; off <<= 1)
                            mt = fmaxf(mt, __shfl_xor(mt, off));
                        float mnew = fmaxf(mrow[qt][r], mt);
                        float al = __expf(mrow[qt][r] - mnew);
                        mrow[qt][r] = mnew;
                        lsum[qt][r] *= al;
#pragma unroll
                        for (int dt = 0; dt < 4; dt++) o[qt][dt][r] *= al;
                    }
            }

            // exp + per-lane partial row-sum
#pragma unroll
            for (int qt = 0; qt < 2; qt++)
#pragma unroll
                for (int r = 0; r < 4; r++) {
                    float rs = 0.f;
#pragma unroll
                    for (int kt = 0; kt < 4; kt++) {
                        float p = __expf(s[qt][kt][r] - mrow[qt][r]);
                        s[qt][kt][r] = p;
                        rs += p;
                    }
                    lsum[qt][r] += rs;
                }

            // P -> padded LDS slab (conflict-free) -> A-fragments
#pragma unroll
            for (int qt = 0; qt < 2; qt++)
#pragma unroll
                for (int kt = 0; kt < 4; kt++)
#pragma unroll
                    for (int r = 0; r < 4; r++)
                        plds[w][qt * 16 + lg * 4 + r][kt * 16 + lr] = (__bf16)s[qt][kt][r];

            bf16x8 pa[2][2];
#pragma unroll
            for (int qt = 0; qt < 2; qt++)
#pragma unroll
                for (int kh = 0; kh < 2; kh++)
                    pa[qt][kh] = *(const bf16x8*)&plds[w][qt * 16 + lr][kh * 32 + lg * 8];

#pragma unroll
            for (int kh = 0; kh < 2; kh++) {
                bf16x8 vf[4];
#pragma unroll
                for (int dt = 0; dt < 4; dt++)
                    vf[dt] = *(const bf16x8*)(Vfp + ((((kt0 * 2 + kh) * 4) + dt) << 9) + lane * 8);
#pragma unroll
                for (int qt = 0; qt < 2; qt++)
#pragma unroll
                    for (int dt = 0; dt < 4; dt++)
                        o[qt][dt] = MFMA16(pa[qt][kh], vf[dt], o[qt][dt]);
            }
        }

        // final row-sum reduce (once per panel) + normalize + store
#pragma unroll
        for (int qt = 0; qt < 2; qt++)
#pragma unroll
            for (int r = 0; r < 4; r++) {
                float rs = lsum[qt][r];
#pragma unroll
                for (int off = 1; off < 16; off <<= 1)
                    rs += __shfl_xor(rs, off);
                lsum[qt][r] = 1.0f / rs;
            }
#pragma unroll
        for (int qt = 0; qt < 2; qt++)
#pragma unroll
            for (int dt = 0; dt < 4; dt++)
#pragma unroll
                for (int r = 0; r < 4; r++) {
                    int qq = qrow0 + qt * 16 + lg * 4 + r;
                    int dd = dt * 16 + lr;
                    float val = o[qt][dt][r] * lsum[qt][r];
                    ATT[(size_t)(b_ * 2048 + qq) * 1024 + hh * 64 + dd] = (__bf16)val;
                }
    }
}

// ---------------- proj GEMM (m97 structure + XCD-chunked swizzle) ----------------
__global__ __launch_bounds__(256, 2) void proj_gemm(const __bf16* __restrict__ A,
                                                    const __bf16* __restrict__ W,
                                                    const float* __restrict__ bias,
                                                    float* __restrict__ out) {
    const int KD = 1024;
    __shared__ __align__(16) __bf16 As[128 * 32];
    __shared__ __align__(16) __bf16 Bs[128 * 32];
    const int tid = threadIdx.x;
    const int lane = tid & 63, w = tid >> 6;
    const int lr = lane & 15, lg = lane >> 4;
    const int orig = blockIdx.x;                       // 0..511
    const int wgid = (orig & 7) * 64 + (orig >> 3);
    const int row0 = (wgid & 63) * 128, col0 = (wgid >> 6) * 128;
    const int wrow = (w >> 1) * 64, wcol = (w & 1) * 64;
    f32x4 acc[4][4] = {};
    const int c0 = tid, c1 = tid + 256;
    const __bf16* ga0 = A + (size_t)(row0 + (c0 >> 2)) * KD + (c0 & 3) * 8;
    const __bf16* ga1 = A + (size_t)(row0 + (c1 >> 2)) * KD + (c1 & 3) * 8;
    const __bf16* gb0 = W + (size_t)(col0 + (c0 >> 2)) * KD + (c0 & 3) * 8;
    const __bf16* gb1 = W + (size_t)(col0 + (c1 >> 2)) * KD + (c1 & 3) * 8;
    for (int k0 = 0; k0 < KD; k0 += 32) {
        __syncthreads();
        GLD16(ga0 + k0, As + c0 * 8);
        GLD16(ga1 + k0, As + c1 * 8);
        GLD16(gb0 + k0, Bs + c0 * 8);
        GLD16(gb1 + k0, Bs + c1 * 8);
        __syncthreads();
        bf16x8 a[4], b[4];
#pragma unroll
        for (int mi = 0; mi < 4; mi++)
            a[mi] = *(const bf16x8*)&As[(wrow + mi * 16 + lr) * 32 + lg * 8];
#pragma unroll
        for (int ni = 0; ni < 4; ni++)
            b[ni] = *(const bf16x8*)&Bs[(wcol + ni * 16 + lr) * 32 + lg * 8];
#pragma unroll
        for (int mi = 0; mi < 4; mi++)
#pragma unroll
            for (int ni = 0; ni < 4; ni++)
                acc[mi][ni] = MFMA16(a[mi], b[ni], acc[mi][ni]);
    }
#pragma unroll
    for (int mi = 0; mi < 4; mi++)
#pragma unroll
        for (int ni = 0; ni < 4; ni++)
#pragma unroll
            for (int r = 0; r < 4; r++) {
                int m = row0 + wrow + mi * 16 + lg * 4 + r;
                int n = col0 + wcol + ni * 16 + lr;
                out[(size_t)m * 1024 + n] = acc[mi][ni][r] + bias[n];
            }
}

extern "C" void kernel_launch(void* const* d_in, const int* in_sizes, int n_in,
                              void* d_out, int out_size, void* d_ws, size_t ws_size,
                              hipStream_t stream) {
    const float* x      = (const float*)d_in[0];
    const float* qkv_w  = (const float*)d_in[1];
    const float* qkv_b  = (const float*)d_in[2];
    const float* proj_w = (const float*)d_in[3];
    const float* proj_b = (const float*)d_in[4];
    float* out = (float*)d_out;
    char* ws = (char*)d_ws;

    __bf16* xb    = (__bf16*)(ws);                         // 16 MB (reused as attb)
    __bf16* wqkv  = (__bf16*)(ws + 16777216);              //  6 MB
    __bf16* wproj = (__bf16*)(ws + 23068672);              //  2 MB
    __bf16* qb    = (__bf16*)(ws + 25165824);              // 16 MB
    __bf16* kfb   = (__bf16*)(ws + 41943040);              // 16 MB (fragment-native K)
    __bf16* vfb   = (__bf16*)(ws + 58720256);              // 16 MB (fragment-native V)
    __bf16* attb  = xb;

    cvt3_f32_bf16<<<2048, 256, 0, stream>>>(x, xb, 4 * 2048 * 1024,
                                            qkv_w, wqkv, 3072 * 1024,
                                            proj_w, wproj, 1024 * 1024);
    qkv_gemm<<<1536, 256, 0, stream>>>(xb, wqkv, qkv_b, qb, kfb, vfb);
    attn_kernel<<<512, 256, 0, stream>>>(qb, kfb, vfb, attb);
    proj_gemm<<<512, 256, 0, stream>>>(attb, wproj, proj_b, out);
}